// Round 7
// baseline (80.905 us; speedup 1.0000x reference)
//
#include <hip/hip_runtime.h>
#include <hip/hip_bf16.h>

#define B_ 32
#define D_ 512
#define N_ 1024
#define M_ 1024
#define BM 128
#define BK 64
#define NSTEP (D_ / BK)   // 8

typedef __attribute__((ext_vector_type(8))) short bf16x8;
typedef __attribute__((ext_vector_type(4))) short s16x4;
typedef __attribute__((ext_vector_type(4))) float f32x4;
typedef __attribute__((ext_vector_type(4))) int   i32x4;
typedef unsigned short ushort_t;

__device__ __forceinline__ unsigned map_f(float f) {
    unsigned b = __float_as_uint(f);
    return (b & 0x80000000u) ? ~b : (b | 0x80000000u);
}

// ============================================================================
// Pass 1: streaming cvt fp32 [b][d][n] -> bf16 [b][d][n].
// PERSISTENT grid-stride version: 1024 blocks (4/CU) resident for the whole
// kernel, each thread walks 32 float4 chunks with depth-2 rotating prefetch.
// Continuous load issue, no block churn, no bursty drain.
// ============================================================================
__device__ __forceinline__ void cvt_store(uint2* d2, size_t idx, const float4& f) {
    __hip_bfloat162 h0 = __float22bfloat162_rn(make_float2(f.x, f.y));
    __hip_bfloat162 h1 = __float22bfloat162_rn(make_float2(f.z, f.w));
    d2[idx] = make_uint2(*reinterpret_cast<const unsigned*>(&h0),
                         *reinterpret_cast<const unsigned*>(&h1));
}

__global__ __launch_bounds__(256)
void cvt_stream_kernel(const float* __restrict__ e1, const float* __restrict__ e2,
                       ushort_t* __restrict__ w1, ushort_t* __restrict__ w2) {
    const float* src = blockIdx.y ? e2 : e1;
    ushort_t*    dst = blockIdx.y ? w2 : w1;
    const float4* s4 = reinterpret_cast<const float4*>(src);
    uint2*        d2 = reinterpret_cast<uint2*>(dst);

    // per array: 4,194,304 float4; 512 blocks x 256 threads; stride 131072;
    // 32 chunks per thread = 15 main iters x 2 + prologue/epilogue 2.
    size_t idx = (size_t)blockIdx.x * 256 + threadIdx.x;
    const size_t STR = 512 * 256;

    float4 b0 = s4[idx];
    float4 b1 = s4[idx + STR];
    #pragma unroll 1
    for (int it = 0; it < 15; ++it) {
        float4 n0 = s4[idx + 2 * STR];   // prefetch ahead of the stores
        float4 n1 = s4[idx + 3 * STR];
        cvt_store(d2, idx, b0);
        cvt_store(d2, idx + STR, b1);
        b0 = n0; b1 = n1;
        idx += 2 * STR;
    }
    cvt_store(d2, idx, b0);
    cvt_store(d2, idx + STR, b1);
}

// ============================================================================
// Pass 2: bf16 GEMM-max from [b][d][n] bf16 workspace.  (unchanged from R5)
// LDS tile [k=64][j=128] bf16 (256B rows), 16B-granule swizzle Q' = Q ^ 2*(k&3).
// Staged via global_load_lds (linear dest + inverse-swizzled global source).
// Fragments gathered with ds_read_b64_tr_b16 (HW transpose read).
// ============================================================================
struct __align__(16) GSmem {
    ushort_t As[2][BM * BK];   // As[0]@0, As[1]@16384, Bs[0]@32768, Bs[1]@49152
    ushort_t Bs[2][BM * BK];
    float red[4];
};

__device__ __forceinline__ void stage_lds(const ushort_t* __restrict__ gpanel, int k0,
                                          ushort_t* lds_tile, int wave, int lane) {
    #pragma unroll
    for (int i = 0; i < 4; ++i) {
        const int reg = wave * 4 + i;            // 16 regions of 4 k-rows
        const int k   = k0 + reg * 4 + (lane >> 4);
        const int Q   = (lane & 15) ^ (2 * (k & 3));
        const char* gp = (const char*)gpanel + (size_t)k * (N_ * 2) + Q * 16;
        char* lp = (char*)lds_tile + reg * 1024;  // wave-uniform base (+lane*16 implicit)
        __builtin_amdgcn_global_load_lds(
            (const __attribute__((address_space(1))) unsigned int*)gp,
            (__attribute__((address_space(3))) unsigned int*)lp, 16, 0, 0);
    }
}

__global__ __launch_bounds__(256, 2)
void gemm_bf16_kernel(const ushort_t* __restrict__ w1, const ushort_t* __restrict__ w2,
                      float* __restrict__ out) {
    __shared__ GSmem sm;
    const int wg  = blockIdx.x;
    const int swz = (wg & 7) * 256 + (wg >> 3);   // XCD swizzle (2048 % 8 == 0)
    const int b    = swz >> 6;
    const int tile = swz & 63;
    const int tn = (tile >> 3) * BM;
    const int tc = (tile & 7) * BM;

    const int t    = threadIdx.x;
    const int lane = t & 63;
    const int wave = t >> 6;
    const int wr   = (wave >> 1) * 64;   // A j-quadrant
    const int wc   = (wave & 1) * 64;    // B j-quadrant

    // tr_read per-lane geometry
    const int c = lane & 15, g = lane >> 4;
    const int r = c >> 2, d = (c >> 1) & 1, h = c & 1;

    const unsigned ldsA0 = (unsigned)(uintptr_t)&sm.As[0][0];
    unsigned tbA[4], tbB[4];
    #pragma unroll
    for (int m = 0; m < 4; ++m)
        tbA[m] = ldsA0 + (8 * g + r) * 256
               + 16 * ((((wr >> 3) + 2 * m + d) ^ (2 * r))) + 8 * h;
    #pragma unroll
    for (int n = 0; n < 4; ++n)
        tbB[n] = ldsA0 + 32768 + (8 * g + r) * 256
               + 16 * ((((wc >> 3) + 2 * n + d) ^ (2 * r))) + 8 * h;

    const ushort_t* Ap = w1 + (size_t)b * D_ * N_ + tn;
    const ushort_t* Bp = w2 + (size_t)b * D_ * M_ + tc;

    f32x4 acc[4][4] = {};

    stage_lds(Ap, 0, sm.As[0], wave, lane);
    stage_lds(Bp, 0, sm.Bs[0], wave, lane);
    asm volatile("s_waitcnt vmcnt(0)" ::: "memory");
    __syncthreads();

    int cur = 0;
    #pragma unroll 1
    for (int ks = 0; ks < NSTEP; ++ks) {
        if (ks < NSTEP - 1) {   // async prefetch of next K-tile into the other buffer
            stage_lds(Ap, (ks + 1) * BK, sm.As[cur ^ 1], wave, lane);
            stage_lds(Bp, (ks + 1) * BK, sm.Bs[cur ^ 1], wave, lane);
        }
        const unsigned off = (unsigned)cur * 16384u;
        #pragma unroll
        for (int kk = 0; kk < 2; ++kk) {
            s16x4 alo[4], ahi[4], blo[4], bhi[4];
            #pragma unroll
            for (int m = 0; m < 4; ++m) {
                asm volatile("ds_read_b64_tr_b16 %0, %1 offset:%2"
                             : "=v"(alo[m]) : "v"(tbA[m] + off), "n"(kk * 8192));
                asm volatile("ds_read_b64_tr_b16 %0, %1 offset:%2"
                             : "=v"(ahi[m]) : "v"(tbA[m] + off), "n"(kk * 8192 + 1024));
            }
            #pragma unroll
            for (int n = 0; n < 4; ++n) {
                asm volatile("ds_read_b64_tr_b16 %0, %1 offset:%2"
                             : "=v"(blo[n]) : "v"(tbB[n] + off), "n"(kk * 8192));
                asm volatile("ds_read_b64_tr_b16 %0, %1 offset:%2"
                             : "=v"(bhi[n]) : "v"(tbB[n] + off), "n"(kk * 8192 + 1024));
            }
            asm volatile("s_waitcnt lgkmcnt(0)" ::: "memory");
            __builtin_amdgcn_sched_barrier(0);
            bf16x8 af[4], bf[4];
            #pragma unroll
            for (int m = 0; m < 4; ++m)
                af[m] = __builtin_shufflevector(alo[m], ahi[m], 0, 1, 2, 3, 4, 5, 6, 7);
            #pragma unroll
            for (int n = 0; n < 4; ++n)
                bf[n] = __builtin_shufflevector(blo[n], bhi[n], 0, 1, 2, 3, 4, 5, 6, 7);
            #pragma unroll
            for (int m = 0; m < 4; ++m)
                #pragma unroll
                for (int n = 0; n < 4; ++n)
                    acc[m][n] = __builtin_amdgcn_mfma_f32_16x16x32_bf16(
                        af[m], bf[n], acc[m][n], 0, 0, 0);
        }
        asm volatile("s_waitcnt vmcnt(0)" ::: "memory");   // prefetched tile landed
        __syncthreads();
        cur ^= 1;
    }

    float tmax = acc[0][0][0];
    #pragma unroll
    for (int m = 0; m < 4; ++m)
        #pragma unroll
        for (int n = 0; n < 4; ++n)
            #pragma unroll
            for (int i = 0; i < 4; ++i)
                tmax = fmaxf(tmax, acc[m][n][i]);
    #pragma unroll
    for (int off2 = 32; off2; off2 >>= 1)
        tmax = fmaxf(tmax, __shfl_xor(tmax, off2));
    if (lane == 0) sm.red[wave] = tmax;
    __syncthreads();
    if (t == 0) {
        float m4 = fmaxf(fmaxf(sm.red[0], sm.red[1]), fmaxf(sm.red[2], sm.red[3]));
        atomicMax(reinterpret_cast<unsigned*>(out) + b, map_f(m4));
    }
}

// ============================================================================
// Fallback (ws too small): round-2 fused fp32->bf16 staging kernel.
// ============================================================================
struct __align__(16) FSmem {
    ushort_t As[2][BM * BK];
    ushort_t Bs[2][BM * BK];
    float red[4];
};

__device__ __forceinline__ void load8(const float* __restrict__ src, int t, float4* fl) {
    const int q  = t & 7;
    const int jg = t >> 3;
    const float* p = src + (size_t)(q * 8) * N_ + jg * 4;
    #pragma unroll
    for (int dd = 0; dd < 8; ++dd)
        fl[dd] = *reinterpret_cast<const float4*>(p + (size_t)dd * N_);
}

__device__ __forceinline__ void flush8(const float4* fl, char* lds, int t) {
    const int q  = t & 7;
    const int jg = t >> 3;
    #pragma unroll
    for (int i = 0; i < 4; ++i) {
        const int j = jg * 4 + i;
        unsigned w[4];
        #pragma unroll
        for (int wi = 0; wi < 4; ++wi) {
            float2 f2 = make_float2(reinterpret_cast<const float*>(&fl[2 * wi])[i],
                                    reinterpret_cast<const float*>(&fl[2 * wi + 1])[i]);
            __hip_bfloat162 h2 = __float22bfloat162_rn(f2);
            w[wi] = *reinterpret_cast<unsigned*>(&h2);
        }
        i32x4 vv = { (int)w[0], (int)w[1], (int)w[2], (int)w[3] };
        *reinterpret_cast<i32x4*>(lds + j * 128 + 16 * (q ^ (j & 7))) = vv;
    }
}

__global__ __launch_bounds__(256, 2)
void gemm_max_kernel(const float* __restrict__ e1, const float* __restrict__ e2,
                     float* __restrict__ out) {
    __shared__ FSmem sm;
    const int wg  = blockIdx.x;
    const int swz = (wg & 7) * 256 + (wg >> 3);
    const int b    = swz >> 6;
    const int tile = swz & 63;
    const int tn = (tile >> 3) * BM;
    const int tc = (tile & 7) * BM;
    const int t    = threadIdx.x;
    const int lane = t & 63;
    const int wave = t >> 6;
    const int l15  = lane & 15;
    const int l4   = lane >> 4;
    const int wr   = (wave >> 1) * 64;
    const int wc   = (wave & 1) * 64;
    const float* e1b = e1 + (size_t)b * D_ * N_ + tn;
    const float* e2b = e2 + (size_t)b * D_ * M_ + tc;
    f32x4 acc[4][4] = {};
    float4 flA[8], flB[8];
    load8(e1b, t, flA);
    load8(e2b, t, flB);
    flush8(flA, (char*)sm.As[0], t);
    flush8(flB, (char*)sm.Bs[0], t);
    load8(e1b + (size_t)BK * N_, t, flA);
    load8(e2b + (size_t)BK * M_, t, flB);
    int cur = 0;
    #pragma unroll 1
    for (int ks = 0; ks < NSTEP; ++ks) {
        __syncthreads();
        const char* Ab = (const char*)sm.As[cur];
        const char* Bb = (const char*)sm.Bs[cur];
        #pragma unroll
        for (int kk = 0; kk < 2; ++kk) {
            bf16x8 afrag[4], bfrag[4];
            const int q = 4 * kk + l4;
            #pragma unroll
            for (int m = 0; m < 4; ++m) {
                const int j = wr + m * 16 + l15;
                afrag[m] = *reinterpret_cast<const bf16x8*>(Ab + j * 128 + 16 * (q ^ (j & 7)));
            }
            #pragma unroll
            for (int n = 0; n < 4; ++n) {
                const int j = wc + n * 16 + l15;
                bfrag[n] = *reinterpret_cast<const bf16x8*>(Bb + j * 128 + 16 * (q ^ (j & 7)));
            }
            #pragma unroll
            for (int m = 0; m < 4; ++m)
                #pragma unroll
                for (int n = 0; n < 4; ++n)
                    acc[m][n] = __builtin_amdgcn_mfma_f32_16x16x32_bf16(
                        afrag[m], bfrag[n], acc[m][n], 0, 0, 0);
        }
        if (ks < NSTEP - 1) {
            flush8(flA, (char*)sm.As[cur ^ 1], t);
            flush8(flB, (char*)sm.Bs[cur ^ 1], t);
            if (ks < NSTEP - 2) {
                load8(e1b + (size_t)(ks + 2) * BK * N_, t, flA);
                load8(e2b + (size_t)(ks + 2) * BK * M_, t, flB);
            }
        }
        cur ^= 1;
    }
    float tmax = acc[0][0][0];
    #pragma unroll
    for (int m = 0; m < 4; ++m)
        #pragma unroll
        for (int n = 0; n < 4; ++n)
            #pragma unroll
            for (int i = 0; i < 4; ++i)
                tmax = fmaxf(tmax, acc[m][n][i]);
    #pragma unroll
    for (int off = 32; off; off >>= 1)
        tmax = fmaxf(tmax, __shfl_xor(tmax, off));
    if (lane == 0) sm.red[wave] = tmax;
    __syncthreads();
    if (t == 0) {
        float m4 = fmaxf(fmaxf(sm.red[0], sm.red[1]), fmaxf(sm.red[2], sm.red[3]));
        atomicMax(reinterpret_cast<unsigned*>(out) + b, map_f(m4));
    }
}

__global__ void finalize_kernel(float* out) {
    const int i = threadIdx.x;
    unsigned u = reinterpret_cast<unsigned*>(out)[i];
    out[i] = __uint_as_float((u & 0x80000000u) ? (u ^ 0x80000000u) : ~u);
}

extern "C" void kernel_launch(void* const* d_in, const int* in_sizes, int n_in,
                              void* d_out, int out_size, void* d_ws, size_t ws_size,
                              hipStream_t stream) {
    const float* e1 = (const float*)d_in[0];
    const float* e2 = (const float*)d_in[1];
    float* out = (float*)d_out;

    hipMemsetAsync(d_out, 0, B_ * sizeof(float), stream);  // 0 == -inf under map_f

    const size_t need = (size_t)2 * B_ * N_ * D_ * sizeof(ushort_t);  // 64 MB
    if (ws_size >= need) {
        ushort_t* w1 = (ushort_t*)d_ws;
        ushort_t* w2 = w1 + (size_t)B_ * N_ * D_;
        cvt_stream_kernel<<<dim3(512, 2), 256, 0, stream>>>(e1, e2, w1, w2);
        gemm_bf16_kernel<<<2048, 256, 0, stream>>>(w1, w2, out);
    } else {
        gemm_max_kernel<<<2048, 256, 0, stream>>>(e1, e2, out);
    }
    finalize_kernel<<<1, B_, 0, stream>>>(out);
}

// Round 8
// 71.087 us; speedup vs baseline: 1.1381x; 1.1381x over previous
//
#include <hip/hip_runtime.h>
#include <hip/hip_bf16.h>

#define B_ 32
#define D_ 512
#define N_ 1024
#define M_ 1024
#define BM 128
#define BK 64
#define NSTEP (D_ / BK)   // 8

typedef __attribute__((ext_vector_type(8))) short bf16x8;
typedef __attribute__((ext_vector_type(4))) short s16x4;
typedef __attribute__((ext_vector_type(4))) float f32x4;
typedef __attribute__((ext_vector_type(4))) int   i32x4;
typedef unsigned short ushort_t;

__device__ __forceinline__ unsigned map_f(float f) {
    unsigned b = __float_as_uint(f);
    return (b & 0x80000000u) ? ~b : (b | 0x80000000u);
}

// ============================================================================
// Fused fp32->bf16 GEMM-max. One kernel, no workspace.
// LDS tile [k=64][j=128] bf16, row 256B = 16 granules of 16B; granule gr of
// row k stored at 16*(gr ^ (2*(k&3))) -- same layout the verified tr_read
// compute phase (R5) expects. Staging: reg-load fp32 (full 512B rows,
// coalesced), cvt_pk in reg, swizzled ds_write_b128 (both-sides swizzle OK
// for reg-staged writes).
// ============================================================================
struct __align__(16) GSmem {
    ushort_t As[2][BM * BK];   // As[0]@0, As[1]@16384, Bs[0]@32768, Bs[1]@49152
    ushort_t Bs[2][BM * BK];
    float red[4];
};

// Load this thread's 4 granules (= 8 float4) of a [64][128] fp32 tile slice.
// krb = wave*16 + (lane>>4)*4 ; gr = lane&15. Per it: 16 lanes cover one full
// 512B row contiguously (two interleaved dwordx4 instrs).
__device__ __forceinline__ void load_tile(const float* __restrict__ p, int k0,
                                          int krb, int gr, float4* fl) {
    #pragma unroll
    for (int it = 0; it < 4; ++it) {
        const float* q = p + (size_t)(k0 + krb + it) * N_ + gr * 8;
        fl[2 * it]     = *reinterpret_cast<const float4*>(q);
        fl[2 * it + 1] = *reinterpret_cast<const float4*>(q + 4);
    }
}

// Convert + write this thread's 4 granules into one LDS tile (swizzled).
__device__ __forceinline__ void flush_tile(char* lds, int krb, int gr, const float4* fl) {
    #pragma unroll
    for (int it = 0; it < 4; ++it) {
        const int k = krb + it;
        const float4& f0 = fl[2 * it];
        const float4& f1 = fl[2 * it + 1];
        __hip_bfloat162 h0 = __float22bfloat162_rn(make_float2(f0.x, f0.y));
        __hip_bfloat162 h1 = __float22bfloat162_rn(make_float2(f0.z, f0.w));
        __hip_bfloat162 h2 = __float22bfloat162_rn(make_float2(f1.x, f1.y));
        __hip_bfloat162 h3 = __float22bfloat162_rn(make_float2(f1.z, f1.w));
        i32x4 v = { *reinterpret_cast<const int*>(&h0), *reinterpret_cast<const int*>(&h1),
                    *reinterpret_cast<const int*>(&h2), *reinterpret_cast<const int*>(&h3) };
        *reinterpret_cast<i32x4*>(lds + k * 256 + 16 * (gr ^ (2 * (k & 3)))) = v;
    }
}

__global__ __launch_bounds__(256, 2)
void fused_gemm_max_kernel(const float* __restrict__ e1, const float* __restrict__ e2,
                           float* __restrict__ out) {
    __shared__ GSmem sm;
    const int wg  = blockIdx.x;
    const int swz = (wg & 7) * 256 + (wg >> 3);   // XCD swizzle (2048 % 8 == 0)
    const int b    = swz >> 6;
    const int tile = swz & 63;
    const int tn = (tile >> 3) * BM;
    const int tc = (tile & 7) * BM;

    const int t    = threadIdx.x;
    const int lane = t & 63;
    const int wave = t >> 6;
    const int wr   = (wave >> 1) * 64;   // A j-quadrant
    const int wc   = (wave & 1) * 64;    // B j-quadrant

    // staging geometry
    const int krb = wave * 16 + (lane >> 4) * 4;
    const int gr  = lane & 15;

    // tr_read per-lane geometry (verified in R5)
    const int c = lane & 15, g = lane >> 4;
    const int r = c >> 2, d = (c >> 1) & 1, h = c & 1;

    const unsigned ldsA0 = (unsigned)(uintptr_t)&sm.As[0][0];
    unsigned tbA[4], tbB[4];
    #pragma unroll
    for (int m = 0; m < 4; ++m)
        tbA[m] = ldsA0 + (8 * g + r) * 256
               + 16 * ((((wr >> 3) + 2 * m + d) ^ (2 * r))) + 8 * h;
    #pragma unroll
    for (int n = 0; n < 4; ++n)
        tbB[n] = ldsA0 + 32768 + (8 * g + r) * 256
               + 16 * ((((wc >> 3) + 2 * n + d) ^ (2 * r))) + 8 * h;

    const float* Ap = e1 + (size_t)b * D_ * N_ + tn;
    const float* Bp = e2 + (size_t)b * D_ * M_ + tc;

    f32x4 acc[4][4] = {};
    float4 flA[8], flB[8];

    // Prologue: stage tile 0, then issue loads for tile 1.
    load_tile(Ap, 0, krb, gr, flA);
    load_tile(Bp, 0, krb, gr, flB);
    flush_tile((char*)sm.As[0], krb, gr, flA);
    flush_tile((char*)sm.Bs[0], krb, gr, flB);
    load_tile(Ap, BK, krb, gr, flA);
    load_tile(Bp, BK, krb, gr, flB);
    asm volatile("s_waitcnt lgkmcnt(0)" ::: "memory");
    __builtin_amdgcn_s_barrier();

    int cur = 0;
    #pragma unroll 1
    for (int ks = 0; ks < NSTEP; ++ks) {
        const unsigned off = (unsigned)cur * 16384u;
        #pragma unroll
        for (int kk = 0; kk < 2; ++kk) {
            s16x4 alo[4], ahi[4], blo[4], bhi[4];
            #pragma unroll
            for (int m = 0; m < 4; ++m) {
                asm volatile("ds_read_b64_tr_b16 %0, %1 offset:%2"
                             : "=v"(alo[m]) : "v"(tbA[m] + off), "n"(kk * 8192));
                asm volatile("ds_read_b64_tr_b16 %0, %1 offset:%2"
                             : "=v"(ahi[m]) : "v"(tbA[m] + off), "n"(kk * 8192 + 1024));
            }
            #pragma unroll
            for (int n = 0; n < 4; ++n) {
                asm volatile("ds_read_b64_tr_b16 %0, %1 offset:%2"
                             : "=v"(blo[n]) : "v"(tbB[n] + off), "n"(kk * 8192));
                asm volatile("ds_read_b64_tr_b16 %0, %1 offset:%2"
                             : "=v"(bhi[n]) : "v"(tbB[n] + off), "n"(kk * 8192 + 1024));
            }
            asm volatile("s_waitcnt lgkmcnt(0)" ::: "memory");
            __builtin_amdgcn_sched_barrier(0);
            bf16x8 af[4], bf[4];
            #pragma unroll
            for (int m = 0; m < 4; ++m)
                af[m] = __builtin_shufflevector(alo[m], ahi[m], 0, 1, 2, 3, 4, 5, 6, 7);
            #pragma unroll
            for (int n = 0; n < 4; ++n)
                bf[n] = __builtin_shufflevector(blo[n], bhi[n], 0, 1, 2, 3, 4, 5, 6, 7);
            __builtin_amdgcn_s_setprio(1);
            #pragma unroll
            for (int m = 0; m < 4; ++m)
                #pragma unroll
                for (int n = 0; n < 4; ++n)
                    acc[m][n] = __builtin_amdgcn_mfma_f32_16x16x32_bf16(
                        af[m], bf[n], acc[m][n], 0, 0, 0);
            __builtin_amdgcn_s_setprio(0);
        }
        // T14 write-late: land tile ks+1 (loads issued one compute-phase ago),
        // then issue loads for tile ks+2.
        if (ks < NSTEP - 1) {
            flush_tile((char*)sm.As[cur ^ 1], krb, gr, flA);
            flush_tile((char*)sm.Bs[cur ^ 1], krb, gr, flB);
            if (ks < NSTEP - 2) {
                load_tile(Ap, (ks + 2) * BK, krb, gr, flA);
                load_tile(Bp, (ks + 2) * BK, krb, gr, flB);
            }
        }
        asm volatile("s_waitcnt lgkmcnt(0)" ::: "memory");  // ds_writes visible; no vmcnt drain
        __builtin_amdgcn_s_barrier();
        cur ^= 1;
    }

    // Max over this thread's 64 accumulator values.
    float tmax = acc[0][0][0];
    #pragma unroll
    for (int m = 0; m < 4; ++m)
        #pragma unroll
        for (int n = 0; n < 4; ++n)
            #pragma unroll
            for (int i = 0; i < 4; ++i)
                tmax = fmaxf(tmax, acc[m][n][i]);
    #pragma unroll
    for (int off2 = 32; off2; off2 >>= 1)
        tmax = fmaxf(tmax, __shfl_xor(tmax, off2));
    if (lane == 0) sm.red[wave] = tmax;
    __syncthreads();
    if (t == 0) {
        float m4 = fmaxf(fmaxf(sm.red[0], sm.red[1]), fmaxf(sm.red[2], sm.red[3]));
        atomicMax(reinterpret_cast<unsigned*>(out) + b, map_f(m4));
    }
}

__global__ void finalize_kernel(float* out) {
    const int i = threadIdx.x;
    unsigned u = reinterpret_cast<unsigned*>(out)[i];
    out[i] = __uint_as_float((u & 0x80000000u) ? (u ^ 0x80000000u) : ~u);
}

extern "C" void kernel_launch(void* const* d_in, const int* in_sizes, int n_in,
                              void* d_out, int out_size, void* d_ws, size_t ws_size,
                              hipStream_t stream) {
    const float* e1 = (const float*)d_in[0];
    const float* e2 = (const float*)d_in[1];
    float* out = (float*)d_out;

    hipMemsetAsync(d_out, 0, B_ * sizeof(float), stream);  // 0 == -inf under map_f

    fused_gemm_max_kernel<<<dim3(2048), 256, 0, stream>>>(e1, e2, out);
    finalize_kernel<<<1, B_, 0, stream>>>(out);
}